// Round 3
// baseline (363.374 us; speedup 1.0000x reference)
//
#include <hip/hip_runtime.h>
#include <hip/hip_bf16.h>
#include <math.h>

#define BATCH 8192
#define IMG 784  // 28*28

// ---------------------------------------------------------------------------
// K0: precompute per-class conv0 one-hot tables T[10][3][784] and
// parity-folded deconv1 weights WF4[par][o][uv][cblk] (float4 over channels).
//
// e_input structure: flat f = ch*784 + s; source element k = (3*ch + s) mod 11.
// k==0 -> x pixel, k==t+1 -> 1.0 for class t. For fixed s, residue k lives in
// channel i = 4*(k - s) mod 11  (4 = inv(3) mod 11).
// ---------------------------------------------------------------------------
__global__ __launch_bounds__(256) void precompute_kernel(
    const float* __restrict__ w0,   // [3,11,3,3]
    const float* __restrict__ dw1,  // [3,11,3,3]
    float* __restrict__ T,          // [10,3,784]
    float* __restrict__ WF4)        // [4,3,4,3]*4 floats = 576
{
    const int blk = blockIdx.x, tid = threadIdx.x;
    if (blk < 10) {
        const int t = blk;
        for (int idx = tid; idx < 3 * 784; idx += 256) {
            int o = idx / 784, pix = idx % 784;
            int r = pix / 28, c = pix % 28;
            float acc = 0.f;
#pragma unroll
            for (int dr = 0; dr < 3; ++dr)
#pragma unroll
                for (int dc = 0; dc < 3; ++dc) {
                    int rr = r + dr - 1, cc = c + dc - 1;
                    if (rr < 0 || rr > 27 || cc < 0 || cc > 27) continue;
                    int s = rr * 28 + cc;
                    int i = ((4 * (t + 1 - s)) % 11 + 11) % 11;
                    acc += w0[(o * 11 + i) * 9 + dr * 3 + dc];
                }
            T[(t * 3 + o) * 784 + pix] = acc;
        }
    } else {
        // WF4 flat idx = (((par*3+o)*4+uv)*3+cb)*4+j ; channel = 4*cb+j
        for (int idx = tid; idx < 576; idx += 256) {
            int j = idx & 3;
            int rest = idx >> 2;
            int cb = rest % 3;
            int rest2 = rest / 3;
            int uv = rest2 % 4;
            int rest3 = rest2 / 4;
            int o = rest3 % 3;
            int par = rest3 / 3;
            int ch = cb * 4 + j;
            float acc = 0.f;
            if (ch < 11) {
                int u = uv >> 1, v = uv & 1;
                int pr = par >> 1, pc = par & 1;
                for (int dr = 0; dr < 3; ++dr) {
                    bool rin = (pr == 0) ? (u == 0 ? dr == 0 : dr >= 1)
                                         : (u == 0 ? dr <= 1 : dr == 2);
                    if (!rin) continue;
                    for (int dc = 0; dc < 3; ++dc) {
                        bool cin = (pc == 0) ? (v == 0 ? dc == 0 : dc >= 1)
                                             : (v == 0 ? dc <= 1 : dc == 2);
                        if (cin) acc += dw1[(o * 11 + ch) * 9 + dr * 3 + dc];
                    }
                }
            }
            WF4[idx] = acc;
        }
    }
}

// ---------------------------------------------------------------------------
// K1: encoder — sparse-x conv0 (9 taps) + class table T + conv1 (float4 LDS)
// ---------------------------------------------------------------------------
__global__ __launch_bounds__(256) void encoder_kernel(
    const float* __restrict__ x, const int* __restrict__ cls,
    const float* __restrict__ w0,   // [3,11,3,3]
    const float* __restrict__ w1,   // [1,3,3,3]
    const float* __restrict__ T,    // [10,3,784]
    float* __restrict__ h_out)      // [B,784]
{
    __shared__ float  xs[30 * 30];      // scattered x image, zero border
    __shared__ float4 hs0[30 * 30];     // conv0 out (3ch + pad), zero border
    __shared__ float4 wt[99];           // [tap][ch] -> (w_o0, w_o1, w_o2, 0)

    const int b = blockIdx.x, tid = threadIdx.x;
    const int myc = cls[b];

    // border-only zero (interior fully overwritten)
    for (int i = tid; i < 116; i += 256) {
        int r, c;
        if (i < 30)      { r = 0;  c = i; }
        else if (i < 60) { r = 29; c = i - 30; }
        else if (i < 88) { r = 1 + (i - 60); c = 0; }
        else             { r = 1 + (i - 88); c = 29; }
        xs[r * 30 + c] = 0.f;
        hs0[r * 30 + c] = make_float4(0.f, 0.f, 0.f, 0.f);
    }
    for (int i = tid; i < 99; i += 256) {
        int tap = i / 11, ch = i % 11;
        wt[i] = make_float4(w0[ch * 9 + tap], w0[(11 + ch) * 9 + tap],
                            w0[(22 + ch) * 9 + tap], 0.f);
    }
    // scatter x: xs[s] = x value living at spatial position s
    for (int s = tid; s < 784; s += 256) {
        int ch = (7 * s) % 11;
        int p = (ch * 784 + s) / 11;
        xs[(s / 28 + 1) * 30 + s % 28 + 1] = x[(size_t)b * IMG + p];
    }
    __syncthreads();

    const float* Tc = T + myc * 2352;
    for (int pix = tid; pix < 784; pix += 256) {
        int r = pix / 28, c = pix % 28;
        float a0 = Tc[pix], a1 = Tc[784 + pix], a2 = Tc[1568 + pix];
        int chbase = (9 * r + 7 * c + 6) % 11;
#pragma unroll
        for (int dr = 0; dr < 3; ++dr)
#pragma unroll
            for (int dc = 0; dc < 3; ++dc) {
                const int kk = (9 * dr + 7 * dc) % 11;  // compile-time
                int ch = chbase + kk;
                if (ch >= 11) ch -= 11;
                float v = xs[(r + dr) * 30 + c + dc];
                float4 w = wt[(dr * 3 + dc) * 11 + ch];
                a0 += v * w.x; a1 += v * w.y; a2 += v * w.z;
            }
        hs0[(r + 1) * 30 + c + 1] =
            make_float4(fmaxf(a0, 0.f), fmaxf(a1, 0.f), fmaxf(a2, 0.f), 0.f);
    }
    __syncthreads();

    for (int pix = tid; pix < 784; pix += 256) {
        int r = pix / 28, c = pix % 28;
        float a = 0.f;
#pragma unroll
        for (int dr = 0; dr < 3; ++dr)
#pragma unroll
            for (int dc = 0; dc < 3; ++dc) {
                int t = dr * 3 + dc;
                float4 v = hs0[(r + dr) * 30 + c + dc];
                a += v.x * w1[t] + v.y * w1[9 + t] + v.z * w1[18 + t];
            }
        h_out[(size_t)b * IMG + pix] = fmaxf(a, 0.f);
    }
}

// ---------------------------------------------------------------------------
// K2: fc1 GEMM  h1[8192,400] = relu(h[8192,784] @ w^T + b)
// ---------------------------------------------------------------------------
__global__ __launch_bounds__(256) void fc1_gemm(
    const float* __restrict__ h, const float* __restrict__ w,
    const float* __restrict__ bias, float* __restrict__ h1)
{
    __shared__ float As[16][64];
    __shared__ float Bs[16][64];

    const int tid = threadIdx.x;
    const int bm = blockIdx.x * 64;
    const int bn = blockIdx.y * 64;
    const int mt = tid % 16;
    const int nt = tid / 16;
    const int lr = tid / 4;
    const int lk = (tid % 4) * 4;

    float acc[4][4] = {};

    for (int k0 = 0; k0 < 784; k0 += 16) {
        float4 a4 = *(const float4*)&h[(size_t)(bm + lr) * 784 + k0 + lk];
        float4 b4 = make_float4(0.f, 0.f, 0.f, 0.f);
        if (bn + lr < 400)
            b4 = *(const float4*)&w[(size_t)(bn + lr) * 784 + k0 + lk];
        __syncthreads();
        As[lk + 0][lr] = a4.x; As[lk + 1][lr] = a4.y;
        As[lk + 2][lr] = a4.z; As[lk + 3][lr] = a4.w;
        Bs[lk + 0][lr] = b4.x; Bs[lk + 1][lr] = b4.y;
        Bs[lk + 2][lr] = b4.z; Bs[lk + 3][lr] = b4.w;
        __syncthreads();
#pragma unroll
        for (int kk = 0; kk < 16; ++kk) {
            float4 av = *(const float4*)&As[kk][mt * 4];
            float4 bv = *(const float4*)&Bs[kk][nt * 4];
            float am[4] = {av.x, av.y, av.z, av.w};
            float bn_[4] = {bv.x, bv.y, bv.z, bv.w};
#pragma unroll
            for (int im = 0; im < 4; ++im)
#pragma unroll
                for (int in_ = 0; in_ < 4; ++in_)
                    acc[im][in_] += am[im] * bn_[in_];
        }
    }

#pragma unroll
    for (int im = 0; im < 4; ++im) {
        int row = bm + mt * 4 + im;
#pragma unroll
        for (int in_ = 0; in_ < 4; ++in_) {
            int col = bn + nt * 4 + in_;
            if (col < 400)
                h1[(size_t)row * 400 + col] = fmaxf(acc[im][in_] + bias[col], 0.f);
        }
    }
}

// ---------------------------------------------------------------------------
// K3: fc21 + fc22 fused
// ---------------------------------------------------------------------------
__global__ __launch_bounds__(320) void fc2_kernel(
    const float* __restrict__ h1,
    const float* __restrict__ w21, const float* __restrict__ b21,
    const float* __restrict__ w22, const float* __restrict__ b22,
    float* __restrict__ out)
{
    __shared__ float hs[16 * 400];
    const int b0 = blockIdx.x * 16;
    const int tid = threadIdx.x;

    for (int i = tid; i < 16 * 400; i += 320)
        hs[i] = h1[(size_t)b0 * 400 + i];
    __syncthreads();

    const int row = tid / 20;
    const int j = tid % 20;

    float a1 = b21[j], a2 = b22[j];
    const float4* hrow = (const float4*)&hs[row * 400];
    const float4* wa = (const float4*)&w21[j * 400];
    const float4* wb = (const float4*)&w22[j * 400];
#pragma unroll 4
    for (int k = 0; k < 100; ++k) {
        float4 hv = hrow[k];
        float4 va = wa[k];
        float4 vb = wb[k];
        a1 += hv.x * va.x + hv.y * va.y + hv.z * va.z + hv.w * va.w;
        a2 += hv.x * vb.x + hv.y * vb.y + hv.z * vb.z + hv.w * vb.w;
    }
    size_t base = (size_t)BATCH * IMG;
    out[base + (size_t)(b0 + row) * 20 + j] = a1;
    out[base + (size_t)BATCH * 20 + (size_t)(b0 + row) * 20 + j] = a2;
}

// ---------------------------------------------------------------------------
// K4: decoder — fc3 + deconv0(ch-minor) + deconv1(q-scheme, scalar-pipe
// weights) + deconv2(float4) + sigmoid
// ---------------------------------------------------------------------------
__global__ __launch_bounds__(256) void decoder_kernel(
    const int* __restrict__ cls,
    const float* __restrict__ fc3_w,  // [392,30]
    const float* __restrict__ fc3_b,  // [392]
    const float* __restrict__ dw0,    // [11,2,3,3]
    const float* __restrict__ dw2,    // [1,3,3,3]
    const float* __restrict__ WF4g,   // 576 floats = 144 float4
    float* __restrict__ out)
{
    __shared__ float  z[32];
    __shared__ float4 d0in4[136];       // [2][16][17] f32, aliased
    __shared__ float4 d0s[16 * 16 * 3]; // [pos 16x16][cblk 0..2] ch-minor
    __shared__ float4 d1s[30 * 30];     // [30][30] (3ch + pad)

    float* d0inS = (float*)d0in4;

    const int b = blockIdx.x;
    const int tid = threadIdx.x;
    const int myc = cls[b];
    const float* mu = out + (size_t)BATCH * IMG + (size_t)b * 20;
    const float4* WF = (const float4*)WF4g;

    // zero d0in fully (small), d0s + d1s borders only
    for (int i = tid; i < 136; i += 256) d0in4[i] = make_float4(0.f, 0.f, 0.f, 0.f);
    for (int i = tid; i < 60; i += 256) {
        int r, c;
        if (i < 16)      { r = 0;  c = i; }
        else if (i < 32) { r = 15; c = i - 16; }
        else if (i < 46) { r = 1 + (i - 32); c = 0; }
        else             { r = 1 + (i - 46); c = 15; }
        int base = (r * 16 + c) * 3;
        d0s[base] = d0s[base + 1] = d0s[base + 2] = make_float4(0.f, 0.f, 0.f, 0.f);
    }
    for (int i = tid; i < 116; i += 256) {
        int r, c;
        if (i < 30)      { r = 0;  c = i; }
        else if (i < 60) { r = 29; c = i - 30; }
        else if (i < 88) { r = 1 + (i - 60); c = 0; }
        else             { r = 1 + (i - 88); c = 29; }
        d1s[r * 30 + c] = make_float4(0.f, 0.f, 0.f, 0.f);
    }
    if (tid < 20) z[tid] = mu[tid];
    else if (tid < 30) z[tid] = (tid - 20 == myc) ? 1.f : 0.f;
    __syncthreads();

    // fc3: [30] -> [392] + relu -> d0in [2][16][17] padded
    for (int j = tid; j < 392; j += 256) {
        float acc = fc3_b[j];
        const float2* wrow = (const float2*)&fc3_w[j * 30];
#pragma unroll
        for (int k = 0; k < 15; ++k) {
            float2 wv = wrow[k];
            acc += z[2 * k] * wv.x + z[2 * k + 1] * wv.y;
        }
        int ch = j / 196, rem = j % 196;
        d0inS[ch * 272 + (rem / 14 + 1) * 17 + (rem % 14 + 1)] = fmaxf(acc, 0.f);
    }
    __syncthreads();

    // deconv0: one thread per position, all 11 channels; weights -> s_loads
    if (tid < 196) {
        int r = tid / 14, c = tid % 14;
        float a[12] = {};
#pragma unroll
        for (int i = 0; i < 2; ++i)
#pragma unroll
            for (int dr = 0; dr < 3; ++dr)
#pragma unroll
                for (int dc = 0; dc < 3; ++dc) {
                    float v = d0inS[i * 272 + (r + dr) * 17 + (c + dc)];
#pragma unroll
                    for (int o = 0; o < 11; ++o)
                        a[o] += v * dw0[((o * 2 + i) * 3 + dr) * 3 + dc];
                }
        int base = ((r + 1) * 16 + (c + 1)) * 3;
        d0s[base + 0] = make_float4(fmaxf(a[0], 0.f), fmaxf(a[1], 0.f),
                                    fmaxf(a[2], 0.f), fmaxf(a[3], 0.f));
        d0s[base + 1] = make_float4(fmaxf(a[4], 0.f), fmaxf(a[5], 0.f),
                                    fmaxf(a[6], 0.f), fmaxf(a[7], 0.f));
        d0s[base + 2] = make_float4(fmaxf(a[8], 0.f), fmaxf(a[9], 0.f),
                                    fmaxf(a[10], 0.f), 0.f);
    }
    __syncthreads();

    // deconv1: one thread per q-position computes all 4 parities.
    // 3x3 float4 window shared across parities; weights via scalar pipe.
    if (tid < 196) {
        int qr = tid / 14, qc = tid % 14;
        float a[4][3] = {};
#pragma unroll
        for (int cb = 0; cb < 3; ++cb) {
            float4 W[3][3];
#pragma unroll
            for (int u = 0; u < 3; ++u)
#pragma unroll
                for (int v = 0; v < 3; ++v)
                    W[u][v] = d0s[((qr + u) * 16 + qc + v) * 3 + cb];
#pragma unroll
            for (int par = 0; par < 4; ++par) {
                int pr = par >> 1, pc = par & 1;
#pragma unroll
                for (int o = 0; o < 3; ++o)
#pragma unroll
                    for (int uv = 0; uv < 4; ++uv) {
                        int u2 = uv >> 1, v2 = uv & 1;
                        float4 wv = WF[((par * 3 + o) * 4 + uv) * 3 + cb];
                        float4 vv = W[pr + u2][pc + v2];
                        a[par][o] += vv.x * wv.x + vv.y * wv.y +
                                     vv.z * wv.z + vv.w * wv.w;
                    }
            }
        }
#pragma unroll
        for (int par = 0; par < 4; ++par) {
            int pr = par >> 1, pc = par & 1;
            int r = 2 * qr + pr + 1, c = 2 * qc + pc + 1;
            d1s[r * 30 + c] = make_float4(fmaxf(a[par][0], 0.f),
                                          fmaxf(a[par][1], 0.f),
                                          fmaxf(a[par][2], 0.f), 0.f);
        }
    }
    __syncthreads();

    // deconv2 (3->1) + sigmoid
    for (int pix = tid; pix < 784; pix += 256) {
        int r = pix / 28, c = pix % 28;
        float a = 0.f;
#pragma unroll
        for (int dr = 0; dr < 3; ++dr)
#pragma unroll
            for (int dc = 0; dc < 3; ++dc) {
                int t = dr * 3 + dc;
                float4 v = d1s[(r + dr) * 30 + c + dc];
                a += v.x * dw2[t] + v.y * dw2[9 + t] + v.z * dw2[18 + t];
            }
        out[(size_t)b * IMG + pix] = 1.f / (1.f + expf(-a));
    }
}

// ---------------------------------------------------------------------------
extern "C" void kernel_launch(void* const* d_in, const int* in_sizes, int n_in,
                              void* d_out, int out_size, void* d_ws, size_t ws_size,
                              hipStream_t stream) {
    const float* x     = (const float*)d_in[0];
    const int*   cls   = (const int*)d_in[1];
    const float* w0    = (const float*)d_in[2];
    const float* w1    = (const float*)d_in[3];
    const float* fc1_w = (const float*)d_in[4];
    const float* fc1_b = (const float*)d_in[5];
    const float* w21   = (const float*)d_in[6];
    const float* b21   = (const float*)d_in[7];
    const float* w22   = (const float*)d_in[8];
    const float* b22   = (const float*)d_in[9];
    const float* fc3_w = (const float*)d_in[10];
    const float* fc3_b = (const float*)d_in[11];
    const float* dw0   = (const float*)d_in[12];
    const float* dw1   = (const float*)d_in[13];
    const float* dw2   = (const float*)d_in[14];

    float* out = (float*)d_out;
    float* ws  = (float*)d_ws;
    float* h    = ws;                                     // [8192,784]
    float* h1   = ws + (size_t)BATCH * IMG;               // [8192,400]
    float* T    = h1 + (size_t)BATCH * 400;               // [10,3,784]
    float* WF4  = T + 10 * 3 * 784;                       // [576]

    precompute_kernel<<<11, 256, 0, stream>>>(w0, dw1, T, WF4);
    encoder_kernel<<<BATCH, 256, 0, stream>>>(x, cls, w0, w1, T, h);
    fc1_gemm<<<dim3(BATCH / 64, 7), 256, 0, stream>>>(h, fc1_w, fc1_b, h1);
    fc2_kernel<<<BATCH / 16, 320, 0, stream>>>(h1, w21, b21, w22, b22, out);
    decoder_kernel<<<BATCH, 256, 0, stream>>>(cls, fc3_w, fc3_b, dw0, dw2, WF4, out);
}

// Round 4
// 299.668 us; speedup vs baseline: 1.2126x; 1.2126x over previous
//
#include <hip/hip_runtime.h>
#include <hip/hip_bf16.h>
#include <math.h>

#define BATCH 8192
#define IMG 784  // 28*28

// ---------------------------------------------------------------------------
// K0: precompute per-class conv0 one-hot tables T[10][3][784] and
// parity-folded deconv1 weights WF4[par][o][uv][cblk] (float4 over channels).
//
// e_input structure: flat f = ch*784 + s; source element k = (3*ch + s) mod 11.
// k==0 -> x pixel, k==t+1 -> 1.0 for class t. For fixed s, residue k lives in
// channel i = 4*(k - s) mod 11  (4 = inv(3) mod 11).
// ---------------------------------------------------------------------------
__global__ __launch_bounds__(256) void precompute_kernel(
    const float* __restrict__ w0,   // [3,11,3,3]
    const float* __restrict__ dw1,  // [3,11,3,3]
    float* __restrict__ T,          // [10,3,784]
    float* __restrict__ WF4)        // [4,3,4,3]*4 floats = 576
{
    const int blk = blockIdx.x, tid = threadIdx.x;
    if (blk < 10) {
        const int t = blk;
        for (int idx = tid; idx < 3 * 784; idx += 256) {
            int o = idx / 784, pix = idx % 784;
            int r = pix / 28, c = pix % 28;
            float acc = 0.f;
#pragma unroll
            for (int dr = 0; dr < 3; ++dr)
#pragma unroll
                for (int dc = 0; dc < 3; ++dc) {
                    int rr = r + dr - 1, cc = c + dc - 1;
                    if (rr < 0 || rr > 27 || cc < 0 || cc > 27) continue;
                    int s = rr * 28 + cc;
                    int i = ((4 * (t + 1 - s)) % 11 + 11) % 11;
                    acc += w0[(o * 11 + i) * 9 + dr * 3 + dc];
                }
            T[(t * 3 + o) * 784 + pix] = acc;
        }
    } else {
        // WF4 flat idx = (((par*3+o)*4+uv)*3+cb)*4+j ; channel = 4*cb+j
        for (int idx = tid; idx < 576; idx += 256) {
            int j = idx & 3;
            int rest = idx >> 2;
            int cb = rest % 3;
            int rest2 = rest / 3;
            int uv = rest2 % 4;
            int rest3 = rest2 / 4;
            int o = rest3 % 3;
            int par = rest3 / 3;
            int ch = cb * 4 + j;
            float acc = 0.f;
            if (ch < 11) {
                int u = uv >> 1, v = uv & 1;
                int pr = par >> 1, pc = par & 1;
                for (int dr = 0; dr < 3; ++dr) {
                    bool rin = (pr == 0) ? (u == 0 ? dr == 0 : dr >= 1)
                                         : (u == 0 ? dr <= 1 : dr == 2);
                    if (!rin) continue;
                    for (int dc = 0; dc < 3; ++dc) {
                        bool cin = (pc == 0) ? (v == 0 ? dc == 0 : dc >= 1)
                                             : (v == 0 ? dc <= 1 : dc == 2);
                        if (cin) acc += dw1[(o * 11 + ch) * 9 + dr * 3 + dc];
                    }
                }
            }
            WF4[idx] = acc;
        }
    }
}

// ---------------------------------------------------------------------------
// K1: encoder — sparse-x conv0 (9 taps) + class table T + conv1 (float4 LDS)
// ---------------------------------------------------------------------------
__global__ __launch_bounds__(256, 4) void encoder_kernel(
    const float* __restrict__ x, const int* __restrict__ cls,
    const float* __restrict__ w0,   // [3,11,3,3]
    const float* __restrict__ w1,   // [1,3,3,3]
    const float* __restrict__ T,    // [10,3,784]
    float* __restrict__ h_out)      // [B,784]
{
    __shared__ float  xs[30 * 30];      // scattered x image, zero border
    __shared__ float4 hs0[30 * 30];     // conv0 out (3ch + pad), zero border
    __shared__ float4 wt[99];           // [tap][ch] -> (w_o0, w_o1, w_o2, 0)

    const int b = blockIdx.x, tid = threadIdx.x;
    const int myc = cls[b];

    // border-only zero (interior fully overwritten)
    for (int i = tid; i < 116; i += 256) {
        int r, c;
        if (i < 30)      { r = 0;  c = i; }
        else if (i < 60) { r = 29; c = i - 30; }
        else if (i < 88) { r = 1 + (i - 60); c = 0; }
        else             { r = 1 + (i - 88); c = 29; }
        xs[r * 30 + c] = 0.f;
        hs0[r * 30 + c] = make_float4(0.f, 0.f, 0.f, 0.f);
    }
    for (int i = tid; i < 99; i += 256) {
        int tap = i / 11, ch = i % 11;
        wt[i] = make_float4(w0[ch * 9 + tap], w0[(11 + ch) * 9 + tap],
                            w0[(22 + ch) * 9 + tap], 0.f);
    }
    // scatter x: xs[s] = x value living at spatial position s
    for (int s = tid; s < 784; s += 256) {
        int ch = (7 * s) % 11;
        int p = (ch * 784 + s) / 11;
        xs[(s / 28 + 1) * 30 + s % 28 + 1] = x[(size_t)b * IMG + p];
    }
    __syncthreads();

    const float* Tc = T + myc * 2352;
    for (int pix = tid; pix < 784; pix += 256) {
        int r = pix / 28, c = pix % 28;
        float a0 = Tc[pix], a1 = Tc[784 + pix], a2 = Tc[1568 + pix];
        int chbase = (9 * r + 7 * c + 6) % 11;
#pragma unroll
        for (int dr = 0; dr < 3; ++dr)
#pragma unroll
            for (int dc = 0; dc < 3; ++dc) {
                const int kk = (9 * dr + 7 * dc) % 11;  // compile-time
                int ch = chbase + kk;
                if (ch >= 11) ch -= 11;
                float v = xs[(r + dr) * 30 + c + dc];
                float4 w = wt[(dr * 3 + dc) * 11 + ch];
                a0 += v * w.x; a1 += v * w.y; a2 += v * w.z;
            }
        hs0[(r + 1) * 30 + c + 1] =
            make_float4(fmaxf(a0, 0.f), fmaxf(a1, 0.f), fmaxf(a2, 0.f), 0.f);
    }
    __syncthreads();

    for (int pix = tid; pix < 784; pix += 256) {
        int r = pix / 28, c = pix % 28;
        float a = 0.f;
#pragma unroll
        for (int dr = 0; dr < 3; ++dr)
#pragma unroll
            for (int dc = 0; dc < 3; ++dc) {
                int t = dr * 3 + dc;
                float4 v = hs0[(r + dr) * 30 + c + dc];
                a += v.x * w1[t] + v.y * w1[9 + t] + v.z * w1[18 + t];
            }
        h_out[(size_t)b * IMG + pix] = fmaxf(a, 0.f);
    }
}

// ---------------------------------------------------------------------------
// K2: fc1 GEMM  h1[8192,400] = relu(h[8192,784] @ w^T + b)
// ---------------------------------------------------------------------------
__global__ __launch_bounds__(256) void fc1_gemm(
    const float* __restrict__ h, const float* __restrict__ w,
    const float* __restrict__ bias, float* __restrict__ h1)
{
    __shared__ float As[16][64];
    __shared__ float Bs[16][64];

    const int tid = threadIdx.x;
    const int bm = blockIdx.x * 64;
    const int bn = blockIdx.y * 64;
    const int mt = tid % 16;
    const int nt = tid / 16;
    const int lr = tid / 4;
    const int lk = (tid % 4) * 4;

    float acc[4][4] = {};

    for (int k0 = 0; k0 < 784; k0 += 16) {
        float4 a4 = *(const float4*)&h[(size_t)(bm + lr) * 784 + k0 + lk];
        float4 b4 = make_float4(0.f, 0.f, 0.f, 0.f);
        if (bn + lr < 400)
            b4 = *(const float4*)&w[(size_t)(bn + lr) * 784 + k0 + lk];
        __syncthreads();
        As[lk + 0][lr] = a4.x; As[lk + 1][lr] = a4.y;
        As[lk + 2][lr] = a4.z; As[lk + 3][lr] = a4.w;
        Bs[lk + 0][lr] = b4.x; Bs[lk + 1][lr] = b4.y;
        Bs[lk + 2][lr] = b4.z; Bs[lk + 3][lr] = b4.w;
        __syncthreads();
#pragma unroll
        for (int kk = 0; kk < 16; ++kk) {
            float4 av = *(const float4*)&As[kk][mt * 4];
            float4 bv = *(const float4*)&Bs[kk][nt * 4];
            float am[4] = {av.x, av.y, av.z, av.w};
            float bn_[4] = {bv.x, bv.y, bv.z, bv.w};
#pragma unroll
            for (int im = 0; im < 4; ++im)
#pragma unroll
                for (int in_ = 0; in_ < 4; ++in_)
                    acc[im][in_] += am[im] * bn_[in_];
        }
    }

#pragma unroll
    for (int im = 0; im < 4; ++im) {
        int row = bm + mt * 4 + im;
#pragma unroll
        for (int in_ = 0; in_ < 4; ++in_) {
            int col = bn + nt * 4 + in_;
            if (col < 400)
                h1[(size_t)row * 400 + col] = fmaxf(acc[im][in_] + bias[col], 0.f);
        }
    }
}

// ---------------------------------------------------------------------------
// K3: fc21 + fc22 fused
// ---------------------------------------------------------------------------
__global__ __launch_bounds__(320) void fc2_kernel(
    const float* __restrict__ h1,
    const float* __restrict__ w21, const float* __restrict__ b21,
    const float* __restrict__ w22, const float* __restrict__ b22,
    float* __restrict__ out)
{
    __shared__ float hs[16 * 400];
    const int b0 = blockIdx.x * 16;
    const int tid = threadIdx.x;

    for (int i = tid; i < 16 * 400; i += 320)
        hs[i] = h1[(size_t)b0 * 400 + i];
    __syncthreads();

    const int row = tid / 20;
    const int j = tid % 20;

    float a1 = b21[j], a2 = b22[j];
    const float4* hrow = (const float4*)&hs[row * 400];
    const float4* wa = (const float4*)&w21[j * 400];
    const float4* wb = (const float4*)&w22[j * 400];
#pragma unroll 4
    for (int k = 0; k < 100; ++k) {
        float4 hv = hrow[k];
        float4 va = wa[k];
        float4 vb = wb[k];
        a1 += hv.x * va.x + hv.y * va.y + hv.z * va.z + hv.w * va.w;
        a2 += hv.x * vb.x + hv.y * vb.y + hv.z * vb.z + hv.w * vb.w;
    }
    size_t base = (size_t)BATCH * IMG;
    out[base + (size_t)(b0 + row) * 20 + j] = a1;
    out[base + (size_t)BATCH * 20 + (size_t)(b0 + row) * 20 + j] = a2;
}

// ---------------------------------------------------------------------------
// K4: decoder — fc3 + deconv0 + wave-parity deconv1 + deconv2 + sigmoid
// ---------------------------------------------------------------------------
__global__ __launch_bounds__(256, 4) void decoder_kernel(
    const int* __restrict__ cls,
    const float* __restrict__ fc3_w,  // [392,30]
    const float* __restrict__ fc3_b,  // [392]
    const float* __restrict__ dw0,    // [11,2,3,3]
    const float* __restrict__ dw2,    // [1,3,3,3]
    const float* __restrict__ WF4g,   // 576 floats = 144 float4
    float* __restrict__ out)
{
    __shared__ float  z[32];
    __shared__ float  d0inS[2 * 16 * 17];  // [2][16][17]
    __shared__ float4 d0sp[3][16 * 16];    // per-cblk planes, ch-minor float4
    __shared__ float4 d1s[30 * 30];        // [30][30] (3ch + pad)
    __shared__ float4 we[144];             // WF copy

    const int b = blockIdx.x;
    const int tid = threadIdx.x;
    const int myc = cls[b];
    const float* mu = out + (size_t)BATCH * IMG + (size_t)b * 20;

    // zero d0in fully; d0sp + d1s borders only
    for (int i = tid; i < 2 * 16 * 17; i += 256) d0inS[i] = 0.f;
    for (int i = tid; i < 60; i += 256) {
        int r, c;
        if (i < 16)      { r = 0;  c = i; }
        else if (i < 32) { r = 15; c = i - 16; }
        else if (i < 46) { r = 1 + (i - 32); c = 0; }
        else             { r = 1 + (i - 46); c = 15; }
        int p = r * 16 + c;
        d0sp[0][p] = d0sp[1][p] = d0sp[2][p] = make_float4(0.f, 0.f, 0.f, 0.f);
    }
    for (int i = tid; i < 116; i += 256) {
        int r, c;
        if (i < 30)      { r = 0;  c = i; }
        else if (i < 60) { r = 29; c = i - 30; }
        else if (i < 88) { r = 1 + (i - 60); c = 0; }
        else             { r = 1 + (i - 88); c = 29; }
        d1s[r * 30 + c] = make_float4(0.f, 0.f, 0.f, 0.f);
    }
    for (int i = tid; i < 144; i += 256) we[i] = ((const float4*)WF4g)[i];
    if (tid < 20) z[tid] = mu[tid];
    else if (tid < 30) z[tid] = (tid - 20 == myc) ? 1.f : 0.f;
    __syncthreads();

    // fc3: [30] -> [392] + relu -> d0in [2][16][17] padded
    for (int j = tid; j < 392; j += 256) {
        float acc = fc3_b[j];
        const float2* wrow = (const float2*)&fc3_w[j * 30];
#pragma unroll
        for (int k = 0; k < 15; ++k) {
            float2 wv = wrow[k];
            acc += z[2 * k] * wv.x + z[2 * k + 1] * wv.y;
        }
        int ch = j / 196, rem = j % 196;
        d0inS[ch * 272 + (rem / 14 + 1) * 17 + (rem % 14 + 1)] = fmaxf(acc, 0.f);
    }
    __syncthreads();

    // deconv0: one thread per position, all 11 channels; weights -> s_loads
    if (tid < 196) {
        int r = tid / 14, c = tid % 14;
        float a[12] = {};
#pragma unroll
        for (int i = 0; i < 2; ++i)
#pragma unroll
            for (int dr = 0; dr < 3; ++dr)
#pragma unroll
                for (int dc = 0; dc < 3; ++dc) {
                    float v = d0inS[i * 272 + (r + dr) * 17 + (c + dc)];
#pragma unroll
                    for (int o = 0; o < 11; ++o)
                        a[o] += v * dw0[((o * 2 + i) * 3 + dr) * 3 + dc];
                }
        int p = (r + 1) * 16 + (c + 1);
        d0sp[0][p] = make_float4(fmaxf(a[0], 0.f), fmaxf(a[1], 0.f),
                                 fmaxf(a[2], 0.f), fmaxf(a[3], 0.f));
        d0sp[1][p] = make_float4(fmaxf(a[4], 0.f), fmaxf(a[5], 0.f),
                                 fmaxf(a[6], 0.f), fmaxf(a[7], 0.f));
        d0sp[2][p] = make_float4(fmaxf(a[8], 0.f), fmaxf(a[9], 0.f),
                                 fmaxf(a[10], 0.f), 0.f);
    }
    __syncthreads();

    // deconv1: wave w owns parity w (wave-uniform -> broadcast weight reads).
    // Each lane-iteration computes one output pixel (3 channels):
    // 12 window ds_read_b128 + 36 broadcast weight reads + 144 FMA.
    {
        const int wid  = tid >> 6;          // parity, wave-uniform
        const int lane = tid & 63;
        const int pr = wid >> 1, pc = wid & 1;
        const float4* wbase = &we[wid * 36];
#pragma unroll 1
        for (int p = 0; p < 4; ++p) {
            int q = p * 64 + lane;
            if (q < 196) {
                int qr = q / 14, qc = q % 14;
                int base0 = (qr + pr) * 16 + qc + pc;
                float a0 = 0.f, a1 = 0.f, a2 = 0.f;
#pragma unroll
                for (int cb = 0; cb < 3; ++cb) {
                    float4 v00 = d0sp[cb][base0];
                    float4 v01 = d0sp[cb][base0 + 1];
                    float4 v10 = d0sp[cb][base0 + 16];
                    float4 v11 = d0sp[cb][base0 + 17];
#pragma unroll
                    for (int o = 0; o < 3; ++o) {
                        float4 w00 = wbase[(o * 4 + 0) * 3 + cb];
                        float4 w01 = wbase[(o * 4 + 1) * 3 + cb];
                        float4 w10 = wbase[(o * 4 + 2) * 3 + cb];
                        float4 w11 = wbase[(o * 4 + 3) * 3 + cb];
                        float s = v00.x * w00.x + v00.y * w00.y +
                                  v00.z * w00.z + v00.w * w00.w +
                                  v01.x * w01.x + v01.y * w01.y +
                                  v01.z * w01.z + v01.w * w01.w +
                                  v10.x * w10.x + v10.y * w10.y +
                                  v10.z * w10.z + v10.w * w10.w +
                                  v11.x * w11.x + v11.y * w11.y +
                                  v11.z * w11.z + v11.w * w11.w;
                        if (o == 0) a0 += s;
                        else if (o == 1) a1 += s;
                        else a2 += s;
                    }
                }
                int r = 2 * qr + pr, c = 2 * qc + pc;
                d1s[(r + 1) * 30 + c + 1] =
                    make_float4(fmaxf(a0, 0.f), fmaxf(a1, 0.f),
                                fmaxf(a2, 0.f), 0.f);
            }
        }
    }
    __syncthreads();

    // deconv2 (3->1) + sigmoid
    for (int pix = tid; pix < 784; pix += 256) {
        int r = pix / 28, c = pix % 28;
        float a = 0.f;
#pragma unroll
        for (int dr = 0; dr < 3; ++dr)
#pragma unroll
            for (int dc = 0; dc < 3; ++dc) {
                int t = dr * 3 + dc;
                float4 v = d1s[(r + dr) * 30 + c + dc];
                a += v.x * dw2[t] + v.y * dw2[9 + t] + v.z * dw2[18 + t];
            }
        out[(size_t)b * IMG + pix] = 1.f / (1.f + expf(-a));
    }
}

// ---------------------------------------------------------------------------
extern "C" void kernel_launch(void* const* d_in, const int* in_sizes, int n_in,
                              void* d_out, int out_size, void* d_ws, size_t ws_size,
                              hipStream_t stream) {
    const float* x     = (const float*)d_in[0];
    const int*   cls   = (const int*)d_in[1];
    const float* w0    = (const float*)d_in[2];
    const float* w1    = (const float*)d_in[3];
    const float* fc1_w = (const float*)d_in[4];
    const float* fc1_b = (const float*)d_in[5];
    const float* w21   = (const float*)d_in[6];
    const float* b21   = (const float*)d_in[7];
    const float* w22   = (const float*)d_in[8];
    const float* b22   = (const float*)d_in[9];
    const float* fc3_w = (const float*)d_in[10];
    const float* fc3_b = (const float*)d_in[11];
    const float* dw0   = (const float*)d_in[12];
    const float* dw1   = (const float*)d_in[13];
    const float* dw2   = (const float*)d_in[14];

    float* out = (float*)d_out;
    float* ws  = (float*)d_ws;
    float* h    = ws;                                     // [8192,784]
    float* h1   = ws + (size_t)BATCH * IMG;               // [8192,400]
    float* T    = h1 + (size_t)BATCH * 400;               // [10,3,784]
    float* WF4  = T + 10 * 3 * 784;                       // [576]

    precompute_kernel<<<11, 256, 0, stream>>>(w0, dw1, T, WF4);
    encoder_kernel<<<BATCH, 256, 0, stream>>>(x, cls, w0, w1, T, h);
    fc1_gemm<<<dim3(BATCH / 64, 7), 256, 0, stream>>>(h, fc1_w, fc1_b, h1);
    fc2_kernel<<<BATCH / 16, 320, 0, stream>>>(h1, w21, b21, w22, b22, out);
    decoder_kernel<<<BATCH, 256, 0, stream>>>(cls, fc3_w, fc3_b, dw0, dw2, WF4, out);
}

// Round 5
// 218.871 us; speedup vs baseline: 1.6602x; 1.3692x over previous
//
#include <hip/hip_runtime.h>
#include <hip/hip_bf16.h>
#include <math.h>

#define BATCH 8192
#define IMG 784   // 28*28
#define KP 800    // fc1 K padded to multiple of 32

typedef short  bf16x8 __attribute__((ext_vector_type(8)));
typedef float  f32x4  __attribute__((ext_vector_type(4)));

// ---------------------------------------------------------------------------
// K0: precompute (a) per-class conv0 one-hot tables T[10][3][784],
// (b) parity-folded deconv1 weights WF4, (c) fc1_w -> bf16 [400][800] padded.
// ---------------------------------------------------------------------------
__global__ __launch_bounds__(256) void precompute_kernel(
    const float* __restrict__ w0,    // [3,11,3,3]
    const float* __restrict__ dw1,   // [3,11,3,3]
    const float* __restrict__ fc1w,  // [400,784]
    float* __restrict__ T,           // [10,3,784]
    float* __restrict__ WF4,         // 576 floats
    __hip_bfloat16* __restrict__ wbf) // [400,800]
{
    const int blk = blockIdx.x, tid = threadIdx.x;
    if (blk < 10) {
        const int t = blk;
        for (int idx = tid; idx < 3 * 784; idx += 256) {
            int o = idx / 784, pix = idx % 784;
            int r = pix / 28, c = pix % 28;
            float acc = 0.f;
#pragma unroll
            for (int dr = 0; dr < 3; ++dr)
#pragma unroll
                for (int dc = 0; dc < 3; ++dc) {
                    int rr = r + dr - 1, cc = c + dc - 1;
                    if (rr < 0 || rr > 27 || cc < 0 || cc > 27) continue;
                    int s = rr * 28 + cc;
                    int i = ((4 * (t + 1 - s)) % 11 + 11) % 11;
                    acc += w0[(o * 11 + i) * 9 + dr * 3 + dc];
                }
            T[(t * 3 + o) * 784 + pix] = acc;
        }
    } else if (blk == 10) {
        // WF4 flat idx = (((par*3+o)*4+uv)*3+cb)*4+j ; channel = 4*cb+j
        for (int idx = tid; idx < 576; idx += 256) {
            int j = idx & 3;
            int rest = idx >> 2;
            int cb = rest % 3;
            int rest2 = rest / 3;
            int uv = rest2 % 4;
            int rest3 = rest2 / 4;
            int o = rest3 % 3;
            int par = rest3 / 3;
            int ch = cb * 4 + j;
            float acc = 0.f;
            if (ch < 11) {
                int u = uv >> 1, v = uv & 1;
                int pr = par >> 1, pc = par & 1;
                for (int dr = 0; dr < 3; ++dr) {
                    bool rin = (pr == 0) ? (u == 0 ? dr == 0 : dr >= 1)
                                         : (u == 0 ? dr <= 1 : dr == 2);
                    if (!rin) continue;
                    for (int dc = 0; dc < 3; ++dc) {
                        bool cin = (pc == 0) ? (v == 0 ? dc == 0 : dc >= 1)
                                             : (v == 0 ? dc <= 1 : dc == 2);
                        if (cin) acc += dw1[(o * 11 + ch) * 9 + dr * 3 + dc];
                    }
                }
            }
            WF4[idx] = acc;
        }
    } else {
        // fc1_w fp32 [400,784] -> bf16 [400,800] (cols 784..799 zero)
        // blocks 11..50, 8000 elements each
        const int base = (blk - 11) * 8000;
        for (int i = tid; i < 8000; i += 256) {
            int flat = base + i;
            int n = flat / KP, k = flat % KP;
            float v = (k < 784) ? fc1w[n * 784 + k] : 0.f;
            wbf[flat] = __float2bfloat16(v);
        }
    }
}

// ---------------------------------------------------------------------------
// K1: encoder — sparse-x conv0 (9 taps) + class table T + conv1 (float4 LDS)
// writes h as bf16 [B][800] (K-padded for MFMA fc1)
// ---------------------------------------------------------------------------
__global__ __launch_bounds__(256, 4) void encoder_kernel(
    const float* __restrict__ x, const int* __restrict__ cls,
    const float* __restrict__ w0,   // [3,11,3,3]
    const float* __restrict__ w1,   // [1,3,3,3]
    const float* __restrict__ T,    // [10,3,784]
    __hip_bfloat16* __restrict__ h_bf)  // [B,800]
{
    __shared__ float  xs[30 * 30];      // scattered x image, zero border
    __shared__ float4 hs0[30 * 30];     // conv0 out (3ch + pad), zero border
    __shared__ float4 wt[99];           // [tap][ch] -> (w_o0, w_o1, w_o2, 0)

    const int b = blockIdx.x, tid = threadIdx.x;
    const int myc = cls[b];

    // border-only zero (interior fully overwritten)
    for (int i = tid; i < 116; i += 256) {
        int r, c;
        if (i < 30)      { r = 0;  c = i; }
        else if (i < 60) { r = 29; c = i - 30; }
        else if (i < 88) { r = 1 + (i - 60); c = 0; }
        else             { r = 1 + (i - 88); c = 29; }
        xs[r * 30 + c] = 0.f;
        hs0[r * 30 + c] = make_float4(0.f, 0.f, 0.f, 0.f);
    }
    for (int i = tid; i < 99; i += 256) {
        int tap = i / 11, ch = i % 11;
        wt[i] = make_float4(w0[ch * 9 + tap], w0[(11 + ch) * 9 + tap],
                            w0[(22 + ch) * 9 + tap], 0.f);
    }
    // scatter x: xs[s] = x value living at spatial position s
    for (int s = tid; s < 784; s += 256) {
        int ch = (7 * s) % 11;
        int p = (ch * 784 + s) / 11;
        xs[(s / 28 + 1) * 30 + s % 28 + 1] = x[(size_t)b * IMG + p];
    }
    // zero the K-pad columns
    if (tid < 16) h_bf[(size_t)b * KP + 784 + tid] = __float2bfloat16(0.f);
    __syncthreads();

    const float* Tc = T + myc * 2352;
    for (int pix = tid; pix < 784; pix += 256) {
        int r = pix / 28, c = pix % 28;
        float a0 = Tc[pix], a1 = Tc[784 + pix], a2 = Tc[1568 + pix];
        int chbase = (9 * r + 7 * c + 6) % 11;
#pragma unroll
        for (int dr = 0; dr < 3; ++dr)
#pragma unroll
            for (int dc = 0; dc < 3; ++dc) {
                const int kk = (9 * dr + 7 * dc) % 11;  // compile-time
                int ch = chbase + kk;
                if (ch >= 11) ch -= 11;
                float v = xs[(r + dr) * 30 + c + dc];
                float4 w = wt[(dr * 3 + dc) * 11 + ch];
                a0 += v * w.x; a1 += v * w.y; a2 += v * w.z;
            }
        hs0[(r + 1) * 30 + c + 1] =
            make_float4(fmaxf(a0, 0.f), fmaxf(a1, 0.f), fmaxf(a2, 0.f), 0.f);
    }
    __syncthreads();

    for (int pix = tid; pix < 784; pix += 256) {
        int r = pix / 28, c = pix % 28;
        float a = 0.f;
#pragma unroll
        for (int dr = 0; dr < 3; ++dr)
#pragma unroll
            for (int dc = 0; dc < 3; ++dc) {
                int t = dr * 3 + dc;
                float4 v = hs0[(r + dr) * 30 + c + dc];
                a += v.x * w1[t] + v.y * w1[9 + t] + v.z * w1[18 + t];
            }
        h_bf[(size_t)b * KP + pix] = __float2bfloat16(fmaxf(a, 0.f));
    }
}

// ---------------------------------------------------------------------------
// K2: fc1 via bf16 MFMA.  h1[8192,400] = relu(h @ w^T + b)
// grid (64 M-blocks, 5 N-blocks); block 256 = 4 waves.
// BM=128 (wave: m_rep=2 x 16 rows), BN=80 (n_rep=5), K-step 32.
// ---------------------------------------------------------------------------
__global__ __launch_bounds__(256) void fc1_mfma(
    const ushort* __restrict__ h_bf,  // [8192,800] bf16
    const ushort* __restrict__ w_bf,  // [400,800] bf16
    const float* __restrict__ bias,   // [400]
    float* __restrict__ h1)           // [8192,400]
{
    __shared__ ushort Bs[80][40];   // B tile [n][k], stride 40 (pad)

    const int tid  = threadIdx.x;
    const int wid  = tid >> 6;
    const int lane = tid & 63;
    const int l15  = lane & 15;
    const int lq   = lane >> 4;       // k-quadrant 0..3
    const int bm   = blockIdx.x * 128;
    const int bn   = blockIdx.y * 80;

    f32x4 acc[2][5] = {};

    const int n0 = tid >> 2;          // 0..63  (staging row)
    const int kq0 = tid & 3;          // staging k-quadrant

    for (int k0 = 0; k0 < KP; k0 += 32) {
        // stage B tile: 80 rows x 32 bf16 (320 x 16B chunks)
        bf16x8 s0 = *(const bf16x8*)&w_bf[(size_t)(bn + n0) * KP + k0 + kq0 * 8];
        bf16x8 s1;
        if (tid < 64)
            s1 = *(const bf16x8*)&w_bf[(size_t)(bn + 64 + n0) * KP + k0 + kq0 * 8];
        // A fragments (global, no LDS dependency)
        bf16x8 a0 = *(const bf16x8*)&h_bf[(size_t)(bm + wid * 32 + l15) * KP + k0 + lq * 8];
        bf16x8 a1 = *(const bf16x8*)&h_bf[(size_t)(bm + wid * 32 + 16 + l15) * KP + k0 + lq * 8];
        __syncthreads();
        *(bf16x8*)&Bs[n0][kq0 * 8] = s0;
        if (tid < 64) *(bf16x8*)&Bs[64 + n0][kq0 * 8] = s1;
        __syncthreads();
#pragma unroll
        for (int nf = 0; nf < 5; ++nf) {
            bf16x8 bfr = *(const bf16x8*)&Bs[nf * 16 + l15][lq * 8];
            acc[0][nf] = __builtin_amdgcn_mfma_f32_16x16x32_bf16(a0, bfr, acc[0][nf], 0, 0, 0);
            acc[1][nf] = __builtin_amdgcn_mfma_f32_16x16x32_bf16(a1, bfr, acc[1][nf], 0, 0, 0);
        }
    }

    // epilogue: row = bm + wid*32 + mr*16 + lq*4 + v ; col = bn + nf*16 + l15
#pragma unroll
    for (int nf = 0; nf < 5; ++nf) {
        int col = bn + nf * 16 + l15;
        float bv = bias[col];
#pragma unroll
        for (int mr = 0; mr < 2; ++mr)
#pragma unroll
            for (int v = 0; v < 4; ++v) {
                int row = bm + wid * 32 + mr * 16 + lq * 4 + v;
                h1[(size_t)row * 400 + col] = fmaxf(acc[mr][nf][v] + bv, 0.f);
            }
    }
}

// ---------------------------------------------------------------------------
// K3: fc21 + fc22 fused
// ---------------------------------------------------------------------------
__global__ __launch_bounds__(320) void fc2_kernel(
    const float* __restrict__ h1,
    const float* __restrict__ w21, const float* __restrict__ b21,
    const float* __restrict__ w22, const float* __restrict__ b22,
    float* __restrict__ out)
{
    __shared__ float hs[16 * 400];
    const int b0 = blockIdx.x * 16;
    const int tid = threadIdx.x;

    for (int i = tid; i < 16 * 400; i += 320)
        hs[i] = h1[(size_t)b0 * 400 + i];
    __syncthreads();

    const int row = tid / 20;
    const int j = tid % 20;

    float a1 = b21[j], a2 = b22[j];
    const float4* hrow = (const float4*)&hs[row * 400];
    const float4* wa = (const float4*)&w21[j * 400];
    const float4* wb = (const float4*)&w22[j * 400];
#pragma unroll 4
    for (int k = 0; k < 100; ++k) {
        float4 hv = hrow[k];
        float4 va = wa[k];
        float4 vb = wb[k];
        a1 += hv.x * va.x + hv.y * va.y + hv.z * va.z + hv.w * va.w;
        a2 += hv.x * vb.x + hv.y * vb.y + hv.z * vb.z + hv.w * vb.w;
    }
    size_t base = (size_t)BATCH * IMG;
    out[base + (size_t)(b0 + row) * 20 + j] = a1;
    out[base + (size_t)BATCH * 20 + (size_t)(b0 + row) * 20 + j] = a2;
}

// ---------------------------------------------------------------------------
// K4: decoder — fc3 + deconv0 + wave-parity deconv1 + deconv2 + sigmoid
// ---------------------------------------------------------------------------
__global__ __launch_bounds__(256, 4) void decoder_kernel(
    const int* __restrict__ cls,
    const float* __restrict__ fc3_w,  // [392,30]
    const float* __restrict__ fc3_b,  // [392]
    const float* __restrict__ dw0,    // [11,2,3,3]
    const float* __restrict__ dw2,    // [1,3,3,3]
    const float* __restrict__ WF4g,   // 576 floats = 144 float4
    float* __restrict__ out)
{
    __shared__ float  z[32];
    __shared__ float  d0inS[2 * 16 * 17];  // [2][16][17]
    __shared__ float4 d0sp[3][16 * 16];    // per-cblk planes, ch-minor float4
    __shared__ float4 d1s[30 * 30];        // [30][30] (3ch + pad)
    __shared__ float4 we[144];             // WF copy

    const int b = blockIdx.x;
    const int tid = threadIdx.x;
    const int myc = cls[b];
    const float* mu = out + (size_t)BATCH * IMG + (size_t)b * 20;

    // zero d0in fully; d0sp + d1s borders only
    for (int i = tid; i < 2 * 16 * 17; i += 256) d0inS[i] = 0.f;
    for (int i = tid; i < 60; i += 256) {
        int r, c;
        if (i < 16)      { r = 0;  c = i; }
        else if (i < 32) { r = 15; c = i - 16; }
        else if (i < 46) { r = 1 + (i - 32); c = 0; }
        else             { r = 1 + (i - 46); c = 15; }
        int p = r * 16 + c;
        d0sp[0][p] = d0sp[1][p] = d0sp[2][p] = make_float4(0.f, 0.f, 0.f, 0.f);
    }
    for (int i = tid; i < 116; i += 256) {
        int r, c;
        if (i < 30)      { r = 0;  c = i; }
        else if (i < 60) { r = 29; c = i - 30; }
        else if (i < 88) { r = 1 + (i - 60); c = 0; }
        else             { r = 1 + (i - 88); c = 29; }
        d1s[r * 30 + c] = make_float4(0.f, 0.f, 0.f, 0.f);
    }
    for (int i = tid; i < 144; i += 256) we[i] = ((const float4*)WF4g)[i];
    if (tid < 20) z[tid] = mu[tid];
    else if (tid < 30) z[tid] = (tid - 20 == myc) ? 1.f : 0.f;
    __syncthreads();

    // fc3: [30] -> [392] + relu -> d0in [2][16][17] padded
    for (int j = tid; j < 392; j += 256) {
        float acc = fc3_b[j];
        const float2* wrow = (const float2*)&fc3_w[j * 30];
#pragma unroll
        for (int k = 0; k < 15; ++k) {
            float2 wv = wrow[k];
            acc += z[2 * k] * wv.x + z[2 * k + 1] * wv.y;
        }
        int ch = j / 196, rem = j % 196;
        d0inS[ch * 272 + (rem / 14 + 1) * 17 + (rem % 14 + 1)] = fmaxf(acc, 0.f);
    }
    __syncthreads();

    // deconv0: one thread per position, all 11 channels; weights -> s_loads
    if (tid < 196) {
        int r = tid / 14, c = tid % 14;
        float a[12] = {};
#pragma unroll
        for (int i = 0; i < 2; ++i)
#pragma unroll
            for (int dr = 0; dr < 3; ++dr)
#pragma unroll
                for (int dc = 0; dc < 3; ++dc) {
                    float v = d0inS[i * 272 + (r + dr) * 17 + (c + dc)];
#pragma unroll
                    for (int o = 0; o < 11; ++o)
                        a[o] += v * dw0[((o * 2 + i) * 3 + dr) * 3 + dc];
                }
        int p = (r + 1) * 16 + (c + 1);
        d0sp[0][p] = make_float4(fmaxf(a[0], 0.f), fmaxf(a[1], 0.f),
                                 fmaxf(a[2], 0.f), fmaxf(a[3], 0.f));
        d0sp[1][p] = make_float4(fmaxf(a[4], 0.f), fmaxf(a[5], 0.f),
                                 fmaxf(a[6], 0.f), fmaxf(a[7], 0.f));
        d0sp[2][p] = make_float4(fmaxf(a[8], 0.f), fmaxf(a[9], 0.f),
                                 fmaxf(a[10], 0.f), 0.f);
    }
    __syncthreads();

    // deconv1: wave w owns parity w (wave-uniform -> broadcast weight reads).
    {
        const int wid  = tid >> 6;          // parity, wave-uniform
        const int lane = tid & 63;
        const int pr = wid >> 1, pc = wid & 1;
        const float4* wbase = &we[wid * 36];
#pragma unroll 1
        for (int p = 0; p < 4; ++p) {
            int q = p * 64 + lane;
            if (q < 196) {
                int qr = q / 14, qc = q % 14;
                int base0 = (qr + pr) * 16 + qc + pc;
                float a0 = 0.f, a1 = 0.f, a2 = 0.f;
#pragma unroll
                for (int cb = 0; cb < 3; ++cb) {
                    float4 v00 = d0sp[cb][base0];
                    float4 v01 = d0sp[cb][base0 + 1];
                    float4 v10 = d0sp[cb][base0 + 16];
                    float4 v11 = d0sp[cb][base0 + 17];
#pragma unroll
                    for (int o = 0; o < 3; ++o) {
                        float4 w00 = wbase[(o * 4 + 0) * 3 + cb];
                        float4 w01 = wbase[(o * 4 + 1) * 3 + cb];
                        float4 w10 = wbase[(o * 4 + 2) * 3 + cb];
                        float4 w11 = wbase[(o * 4 + 3) * 3 + cb];
                        float s = v00.x * w00.x + v00.y * w00.y +
                                  v00.z * w00.z + v00.w * w00.w +
                                  v01.x * w01.x + v01.y * w01.y +
                                  v01.z * w01.z + v01.w * w01.w +
                                  v10.x * w10.x + v10.y * w10.y +
                                  v10.z * w10.z + v10.w * w10.w +
                                  v11.x * w11.x + v11.y * w11.y +
                                  v11.z * w11.z + v11.w * w11.w;
                        if (o == 0) a0 += s;
                        else if (o == 1) a1 += s;
                        else a2 += s;
                    }
                }
                int r = 2 * qr + pr, c = 2 * qc + pc;
                d1s[(r + 1) * 30 + c + 1] =
                    make_float4(fmaxf(a0, 0.f), fmaxf(a1, 0.f),
                                fmaxf(a2, 0.f), 0.f);
            }
        }
    }
    __syncthreads();

    // deconv2 (3->1) + sigmoid
    for (int pix = tid; pix < 784; pix += 256) {
        int r = pix / 28, c = pix % 28;
        float a = 0.f;
#pragma unroll
        for (int dr = 0; dr < 3; ++dr)
#pragma unroll
            for (int dc = 0; dc < 3; ++dc) {
                int t = dr * 3 + dc;
                float4 v = d1s[(r + dr) * 30 + c + dc];
                a += v.x * dw2[t] + v.y * dw2[9 + t] + v.z * dw2[18 + t];
            }
        out[(size_t)b * IMG + pix] = 1.f / (1.f + expf(-a));
    }
}

// ---------------------------------------------------------------------------
extern "C" void kernel_launch(void* const* d_in, const int* in_sizes, int n_in,
                              void* d_out, int out_size, void* d_ws, size_t ws_size,
                              hipStream_t stream) {
    const float* x     = (const float*)d_in[0];
    const int*   cls   = (const int*)d_in[1];
    const float* w0    = (const float*)d_in[2];
    const float* w1    = (const float*)d_in[3];
    const float* fc1_w = (const float*)d_in[4];
    const float* fc1_b = (const float*)d_in[5];
    const float* w21   = (const float*)d_in[6];
    const float* b21   = (const float*)d_in[7];
    const float* w22   = (const float*)d_in[8];
    const float* b22   = (const float*)d_in[9];
    const float* fc3_w = (const float*)d_in[10];
    const float* fc3_b = (const float*)d_in[11];
    const float* dw0   = (const float*)d_in[12];
    const float* dw1   = (const float*)d_in[13];
    const float* dw2   = (const float*)d_in[14];

    float* out = (float*)d_out;
    char*  ws  = (char*)d_ws;
    // layout: h_bf [8192*800 bf16] | h1 [8192*400 f32] | T | WF4 | w_bf
    __hip_bfloat16* h_bf = (__hip_bfloat16*)ws;
    float* h1   = (float*)(ws + (size_t)BATCH * KP * 2);
    float* T    = h1 + (size_t)BATCH * 400;
    float* WF4  = T + 10 * 3 * 784;
    __hip_bfloat16* w_bf = (__hip_bfloat16*)(WF4 + 576);

    precompute_kernel<<<51, 256, 0, stream>>>(w0, dw1, fc1_w, T, WF4, w_bf);
    encoder_kernel<<<BATCH, 256, 0, stream>>>(x, cls, w0, w1, T, h_bf);
    fc1_mfma<<<dim3(64, 5), 256, 0, stream>>>((const ushort*)h_bf,
                                              (const ushort*)w_bf, fc1_b, h1);
    fc2_kernel<<<BATCH / 16, 320, 0, stream>>>(h1, w21, b21, w22, b22, out);
    decoder_kernel<<<BATCH, 256, 0, stream>>>(cls, fc3_w, fc3_b, dw0, dw2, WF4, out);
}